// Round 1
// baseline (577.771 us; speedup 1.0000x reference)
//
#include <hip/hip_runtime.h>

// NaiveLSTM: degenerate LSTM -> one batched pass.
//   gates a_g = X @ W_g + s_g  (s_g constant over b,t)
//   i,f,o = sigmoid, g = tanh; c = f*c0 + i*g; h = o*tanh(c)
// Inputs FLOAT32, outputs FLOAT32 (proven R1/R2: bf16-in => NaN; bf16-out => absmax<=1.94 but saw 2.69).
// Internals: MFMA bf16 (X/W RNE-rounded), fp32 accumulate + fp32 epilogue.
//
// R3: GRID 512->1024 (ITERS 32->16). Prior config was 2 blocks/CU (occupancy
// 18.6%) while VGPR=128 and LDS=34304 both allow 4 blocks/CU; grid size was
// the binding occupancy limit. 1024 blocks = exactly 4 resident blocks/CU.

typedef __attribute__((ext_vector_type(8))) short short8;
typedef __attribute__((ext_vector_type(4))) float f32x4;
typedef __attribute__((ext_vector_type(2))) unsigned int uint2v;

#define GRID  1024
#define CHUNK 32              // rows per iteration per block
#define M_    524288          // B*T
#define ITERS 16              // (M_/CHUNK)/GRID
#define LSTR  272             // A-tile LDS row stride bytes (256 + 16 pad)
#define AB0   0
#define AB1   (32 * LSTR)
#define OB    (2 * 32 * LSTR) // 17408: fp32 out tile base
#define LSTRO 528             // out-tile row stride bytes (512 + 16 pad)
#define LDSSZ (OB + 32 * LSTRO)   // 34304

__device__ __forceinline__ unsigned fbits(float f) {
    union { float f; unsigned u; } v; v.f = f; return v.u;
}
__device__ __forceinline__ unsigned short f2bf(float f) {
    unsigned u = fbits(f);
    return (unsigned short)((u + 0x7FFFu + ((u >> 16) & 1u)) >> 16);
}
__device__ __forceinline__ unsigned packbf2(float a, float b) {
    unsigned ua = fbits(a) , ub = fbits(b);
    ua = ua + 0x7FFFu + ((ua >> 16) & 1u);
    ub = ub + 0x7FFFu + ((ub >> 16) & 1u);
    return (ub & 0xFFFF0000u) | (ua >> 16);
}
__device__ __forceinline__ float clamp30(float x) {
    return fminf(fmaxf(x, -30.f), 30.f);
}

__global__ __launch_bounds__(256, 2)
void lstm_main(const float* __restrict__ x,
               const float* __restrict__ h0,
               const float* __restrict__ c0,
               // gate order: 0=i, 1=f, 2=o, 3=g
               const float* __restrict__ wi0, const float* __restrict__ wh0,
               const float* __restrict__ bi0, const float* __restrict__ bh0,
               const float* __restrict__ wi1, const float* __restrict__ wh1,
               const float* __restrict__ bi1, const float* __restrict__ bh1,
               const float* __restrict__ wi2, const float* __restrict__ wh2,
               const float* __restrict__ bi2, const float* __restrict__ bh2,
               const float* __restrict__ wi3, const float* __restrict__ wh3,
               const float* __restrict__ bi3, const float* __restrict__ bh3,
               float* __restrict__ out)
{
    __shared__ __align__(16) char lds[LDSSZ];
    const int tid  = threadIdx.x;
    const int w    = tid >> 6;          // wave 0..3 -> cols [32w, 32w+32)
    const int lane = tid & 63;
    const int lo   = lane & 15;
    const int hi   = lane >> 4;

    // ---- s_g[col] = h0 . Wh_g[:,col] + bi_g[col] + bh_g[col]  (fp32, cooperative) ----
    float* sbuf = (float*)(lds + OB);
    {
        const int col = tid & 127;
        const int g0  = tid >> 7;                 // 0/1 -> handles gates g0 and g0+2
        const float* whA = g0 ? wh1 : wh0;
        const float* whB = g0 ? wh3 : wh2;
        float aA = (g0 ? bi1[col] : bi0[col]) + (g0 ? bh1[col] : bh0[col]);
        float aB = (g0 ? bi3[col] : bi2[col]) + (g0 ? bh3[col] : bh2[col]);
        #pragma unroll 8
        for (int k = 0; k < 128; ++k) {
            float hk = h0[k];
            aA += hk * whA[k * 128 + col];
            aB += hk * whB[k * 128 + col];
        }
        sbuf[g0 * 128 + col]       = aA;
        sbuf[(g0 + 2) * 128 + col] = aB;
    }
    __syncthreads();

    float sv[2][4], c0v[2];
    #pragma unroll
    for (int nt = 0; nt < 2; ++nt) {
        const int col = w * 32 + nt * 16 + lo;
        #pragma unroll
        for (int g = 0; g < 4; ++g) sv[nt][g] = sbuf[g * 128 + col];
        c0v[nt] = c0[col];
    }

    // ---- B fragments (bf16, RNE) in regs: layout B[k=kt*32+hi*8+j][n=col] ----
    short8 Bf[2][4][4];
    {
        const float* Wi[4] = { wi0, wi1, wi2, wi3 };
        #pragma unroll
        for (int nt = 0; nt < 2; ++nt) {
            const int col = w * 32 + nt * 16 + lo;
            #pragma unroll
            for (int g = 0; g < 4; ++g) {
                #pragma unroll
                for (int kt = 0; kt < 4; ++kt) {
                    short8 v;
                    #pragma unroll
                    for (int j = 0; j < 8; ++j)
                        v[j] = (short)f2bf(Wi[g][(kt * 32 + hi * 8 + j) * 128 + col]);
                    Bf[nt][g][kt] = v;
                }
            }
        }
    }

    // ---- staging: chunk = 32 rows x 128 fp32 = 1024 float4; thread t takes
    //      float4 idx f = j*256+t (j=0..3): row=f>>5, cols 4*(f&31)..+3.
    //      Convert fp32->bf16 (RNE) and store 8B to LDS A-tile. ----
    const float4* xv4 = (const float4*)x;
    int m0 = blockIdx.x * CHUNK;
    {
        #pragma unroll
        for (int j = 0; j < 4; ++j) {
            const int f = j * 256 + tid;
            float4 v = xv4[m0 * 32 + f];
            uint2v p;
            p.x = packbf2(v.x, v.y);
            p.y = packbf2(v.z, v.w);
            *(uint2v*)(lds + AB0 + (f >> 5) * LSTR + (f & 31) * 8) = p;
        }
    }
    __syncthreads();

    float* hseq  = out;                       // (T,B,1,H) = 67108864 floats
    float* hlast = out + 67108864;            // (B,1,H)
    float* clast = out + 67108864 + 32768;    // (B,1,H)

    for (int it = 0; it < ITERS; ++it) {
        const char* Ab = lds + ((it & 1) ? AB1 : AB0);

        float4 pf[4];
        if (it + 1 < ITERS) {
            const int m0n = m0 + GRID * CHUNK;
            #pragma unroll
            for (int j = 0; j < 4; ++j)
                pf[j] = xv4[m0n * 32 + j * 256 + tid];
        }

        f32x4 acc[2][2][4];
        #pragma unroll
        for (int mt = 0; mt < 2; ++mt)
            #pragma unroll
            for (int nt = 0; nt < 2; ++nt)
                #pragma unroll
                for (int g = 0; g < 4; ++g)
                    acc[mt][nt][g] = (f32x4){0.f, 0.f, 0.f, 0.f};

        #pragma unroll
        for (int kt = 0; kt < 4; ++kt) {
            short8 a0 = *(const short8*)(Ab + lo * LSTR + (kt * 4 + hi) * 16);
            short8 a1 = *(const short8*)(Ab + (16 + lo) * LSTR + (kt * 4 + hi) * 16);
            #pragma unroll
            for (int nt = 0; nt < 2; ++nt)
                #pragma unroll
                for (int g = 0; g < 4; ++g) {
                    acc[0][nt][g] = __builtin_amdgcn_mfma_f32_16x16x32_bf16(a0, Bf[nt][g][kt], acc[0][nt][g], 0, 0, 0);
                    acc[1][nt][g] = __builtin_amdgcn_mfma_f32_16x16x32_bf16(a1, Bf[nt][g][kt], acc[1][nt][g], 0, 0, 0);
                }
        }

        // ---- epilogue: activations + combine; fp32 h -> LDS out tile ----
        const bool lastChunk = ((m0 & 2047) == 2016);
        const int  b = m0 >> 11;
        const float K1 = 1.44269504f, K2 = 2.88539008f;
        #pragma unroll
        for (int mt = 0; mt < 2; ++mt)
            #pragma unroll
            for (int nt = 0; nt < 2; ++nt) {
                const int col = w * 32 + nt * 16 + lo;
                #pragma unroll
                for (int reg = 0; reg < 4; ++reg) {
                    float ai = clamp30(acc[mt][nt][0][reg] + sv[nt][0]);
                    float af = clamp30(acc[mt][nt][1][reg] + sv[nt][1]);
                    float ao = clamp30(acc[mt][nt][2][reg] + sv[nt][2]);
                    float ag = clamp30(acc[mt][nt][3][reg] + sv[nt][3]);
                    float ti = __builtin_amdgcn_exp2f(-K1 * ai);
                    float tf = __builtin_amdgcn_exp2f(-K1 * af);
                    float to = __builtin_amdgcn_exp2f(-K1 * ao);
                    float tg = __builtin_amdgcn_exp2f(-K2 * ag);
                    float fg = __builtin_amdgcn_rcpf(1.f + tf);                       // sigmoid(af)
                    float ig = (1.f - tg) * __builtin_amdgcn_rcpf((1.f + ti) * (1.f + tg)); // sig(ai)*tanh(ag)
                    float cv = clamp30(fg * c0v[nt] + ig);
                    float tc = __builtin_amdgcn_exp2f(-K2 * cv);
                    float hv = (1.f - tc) * __builtin_amdgcn_rcpf((1.f + to) * (1.f + tc)); // sig(ao)*tanh(cv)
                    const int r = mt * 16 + hi * 4 + reg;
                    *(float*)(lds + OB + r * LSTRO + col * 4) = hv;
                    if (lastChunk && mt == 1 && reg == 3 && hi == 3)   // row t=2047
                        clast[b * 128 + col] = cv;
                }
            }

        // stage next chunk into other buffer (convert + LDS write)
        if (it + 1 < ITERS) {
            char* An = lds + ((it & 1) ? AB0 : AB1);
            #pragma unroll
            for (int j = 0; j < 4; ++j) {
                const int f = j * 256 + tid;
                uint2v p;
                p.x = packbf2(pf[j].x, pf[j].y);
                p.y = packbf2(pf[j].z, pf[j].w);
                *(uint2v*)(An + (f >> 5) * LSTR + (f & 31) * 8) = p;
            }
        }
        __syncthreads();

        // ---- store: fp32 rows of hidden_seq (T,B,1,H); 512B contiguous per row ----
        #pragma unroll
        for (int j = 0; j < 4; ++j) {
            const int f = j * 256 + tid;        // float4 index in 32x128 tile
            const int r = f >> 5;
            const int c = f & 31;
            float4 vv = *(const float4*)(lds + OB + r * LSTRO + c * 16);
            const int m = m0 + r;
            const int t = m & 2047;
            *(float4*)(hseq + (t * 256 + b) * 128 + c * 4) = vv;
            if (t == 2047)
                *(float4*)(hlast + b * 128 + c * 4) = vv;
        }
        __syncthreads();

        m0 += GRID * CHUNK;
    }
}

extern "C" void kernel_launch(void* const* d_in, const int* in_sizes, int n_in,
                              void* d_out, int out_size, void* d_ws, size_t ws_size,
                              hipStream_t stream) {
    (void)in_sizes; (void)n_in; (void)out_size; (void)d_ws; (void)ws_size;
    const float* x  = (const float*)d_in[0];
    const float* h0 = (const float*)d_in[1];
    const float* c0 = (const float*)d_in[2];
    // setup_inputs order: 3..6 = i (w_ii,w_hi,b_ii,b_hi), 7..10 = f, 11..14 = o, 15..18 = g
    lstm_main<<<dim3(GRID), dim3(256), 0, stream>>>(
        x, h0, c0,
        (const float*)d_in[3],  (const float*)d_in[4],
        (const float*)d_in[5],  (const float*)d_in[6],
        (const float*)d_in[7],  (const float*)d_in[8],
        (const float*)d_in[9],  (const float*)d_in[10],
        (const float*)d_in[11], (const float*)d_in[12],
        (const float*)d_in[13], (const float*)d_in[14],
        (const float*)d_in[15], (const float*)d_in[16],
        (const float*)d_in[17], (const float*)d_in[18],
        (float*)d_out);
}

// Round 2
// 505.106 us; speedup vs baseline: 1.1439x; 1.1439x over previous
//
#include <hip/hip_runtime.h>

// NaiveLSTM: degenerate LSTM -> one batched pass.
//   gates a_g = X @ W_g + s_g  (s_g constant over b,t)
//   i,f,o = sigmoid, g = tanh; c = f*c0 + i*g; h = o*tanh(c)
// Inputs FLOAT32, outputs FLOAT32 (proven R1/R2: bf16-in => NaN; bf16-out => absmax<=1.94 but saw 2.69).
// Internals: MFMA bf16 (X/W RNE-rounded), fp32 accumulate + fp32 epilogue.
//
// R4: occupancy was register-capped, not grid-capped (R3 null result: grid
// 512->1024 left occupancy at 19%). Per-wave regs were ~256 (Bf 128 + acc 64
// + misc) -> 2 waves/SIMD. Restructure: 512-thread blocks, 8 waves, each wave
// 16 cols x 4 gates x 32 rows -> Bf 64 + acc 32 + misc ~= 128 regs ->
// 4 waves/SIMD = 2 resident 8-wave blocks/CU (16 waves). GRID=512 so both
// blocks/CU are resident in one sweep.

typedef __attribute__((ext_vector_type(8))) short short8;
typedef __attribute__((ext_vector_type(4))) float f32x4;
typedef __attribute__((ext_vector_type(2))) unsigned int uint2v;

#define GRID  512
#define THREADS 512
#define CHUNK 32              // rows per iteration per block
#define M_    524288          // B*T
#define ITERS 32              // (M_/CHUNK)/GRID
#define LSTR  272             // A-tile LDS row stride bytes (256 + 16 pad)
#define AB0   0
#define AB1   (32 * LSTR)
#define OB    (2 * 32 * LSTR) // 17408: fp32 out tile base
#define LSTRO 528             // out-tile row stride bytes (512 + 16 pad)
#define LDSSZ (OB + 32 * LSTRO)   // 34304

__device__ __forceinline__ unsigned fbits(float f) {
    union { float f; unsigned u; } v; v.f = f; return v.u;
}
__device__ __forceinline__ unsigned short f2bf(float f) {
    unsigned u = fbits(f);
    return (unsigned short)((u + 0x7FFFu + ((u >> 16) & 1u)) >> 16);
}
__device__ __forceinline__ unsigned packbf2(float a, float b) {
    unsigned ua = fbits(a) , ub = fbits(b);
    ua = ua + 0x7FFFu + ((ua >> 16) & 1u);
    ub = ub + 0x7FFFu + ((ub >> 16) & 1u);
    return (ub & 0xFFFF0000u) | (ua >> 16);
}
__device__ __forceinline__ float clamp30(float x) {
    return fminf(fmaxf(x, -30.f), 30.f);
}

__global__ __launch_bounds__(THREADS, 4)
void lstm_main(const float* __restrict__ x,
               const float* __restrict__ h0,
               const float* __restrict__ c0,
               // gate order: 0=i, 1=f, 2=o, 3=g
               const float* __restrict__ wi0, const float* __restrict__ wh0,
               const float* __restrict__ bi0, const float* __restrict__ bh0,
               const float* __restrict__ wi1, const float* __restrict__ wh1,
               const float* __restrict__ bi1, const float* __restrict__ bh1,
               const float* __restrict__ wi2, const float* __restrict__ wh2,
               const float* __restrict__ bi2, const float* __restrict__ bh2,
               const float* __restrict__ wi3, const float* __restrict__ wh3,
               const float* __restrict__ bi3, const float* __restrict__ bh3,
               float* __restrict__ out)
{
    __shared__ __align__(16) char lds[LDSSZ];
    const int tid  = threadIdx.x;
    const int ww   = tid >> 6;          // wave 0..7 -> cols [16*ww, 16*ww+16)
    const int lane = tid & 63;
    const int lo   = lane & 15;
    const int hi   = lane >> 4;
    const int col  = ww * 16 + lo;      // this lane's output column

    // ---- s_g[col] = h0 . Wh_g[:,col] + bi_g[col] + bh_g[col]  (fp32, cooperative) ----
    // 512 threads x (1 gate, 1 col) each.
    float* sbuf = (float*)(lds + OB);
    {
        const int pc = tid & 127;
        const int g  = tid >> 7;                 // 0..3
        const float* wh = (g == 0) ? wh0 : (g == 1) ? wh1 : (g == 2) ? wh2 : wh3;
        const float* bi = (g == 0) ? bi0 : (g == 1) ? bi1 : (g == 2) ? bi2 : bi3;
        const float* bh = (g == 0) ? bh0 : (g == 1) ? bh1 : (g == 2) ? bh2 : bh3;
        float a = bi[pc] + bh[pc];
        #pragma unroll 8
        for (int k = 0; k < 128; ++k)
            a += h0[k] * wh[k * 128 + pc];
        sbuf[g * 128 + pc] = a;
    }
    __syncthreads();

    float sv[4], c0v;
    #pragma unroll
    for (int g = 0; g < 4; ++g) sv[g] = sbuf[g * 128 + col];
    c0v = c0[col];

    // ---- B fragments (bf16, RNE) in regs: layout B[k=kt*32+hi*8+j][n=col] ----
    short8 Bf[4][4];
    {
        const float* Wi[4] = { wi0, wi1, wi2, wi3 };
        #pragma unroll
        for (int g = 0; g < 4; ++g) {
            #pragma unroll
            for (int kt = 0; kt < 4; ++kt) {
                short8 v;
                #pragma unroll
                for (int j = 0; j < 8; ++j)
                    v[j] = (short)f2bf(Wi[g][(kt * 32 + hi * 8 + j) * 128 + col]);
                Bf[g][kt] = v;
            }
        }
    }

    // ---- staging: chunk = 32 rows x 128 fp32 = 1024 float4; thread t takes
    //      float4 idx f = j*512+t (j=0..1): row=f>>5, cols 4*(f&31)..+3.
    //      Convert fp32->bf16 (RNE) and store 8B to LDS A-tile. ----
    const float4* xv4 = (const float4*)x;
    int m0 = blockIdx.x * CHUNK;
    {
        #pragma unroll
        for (int j = 0; j < 2; ++j) {
            const int f = j * 512 + tid;
            float4 v = xv4[m0 * 32 + f];
            uint2v p;
            p.x = packbf2(v.x, v.y);
            p.y = packbf2(v.z, v.w);
            *(uint2v*)(lds + AB0 + (f >> 5) * LSTR + (f & 31) * 8) = p;
        }
    }
    __syncthreads();

    float* hseq  = out;                       // (T,B,1,H) = 67108864 floats
    float* hlast = out + 67108864;            // (B,1,H)
    float* clast = out + 67108864 + 32768;    // (B,1,H)

    for (int it = 0; it < ITERS; ++it) {
        const char* Ab = lds + ((it & 1) ? AB1 : AB0);

        float4 pf[2];
        if (it + 1 < ITERS) {
            const int m0n = m0 + GRID * CHUNK;
            #pragma unroll
            for (int j = 0; j < 2; ++j)
                pf[j] = xv4[m0n * 32 + j * 512 + tid];
        }

        f32x4 acc[2][4];
        #pragma unroll
        for (int mt = 0; mt < 2; ++mt)
            #pragma unroll
            for (int g = 0; g < 4; ++g)
                acc[mt][g] = (f32x4){0.f, 0.f, 0.f, 0.f};

        #pragma unroll
        for (int kt = 0; kt < 4; ++kt) {
            short8 a0 = *(const short8*)(Ab + lo * LSTR + (kt * 4 + hi) * 16);
            short8 a1 = *(const short8*)(Ab + (16 + lo) * LSTR + (kt * 4 + hi) * 16);
            #pragma unroll
            for (int g = 0; g < 4; ++g) {
                acc[0][g] = __builtin_amdgcn_mfma_f32_16x16x32_bf16(a0, Bf[g][kt], acc[0][g], 0, 0, 0);
                acc[1][g] = __builtin_amdgcn_mfma_f32_16x16x32_bf16(a1, Bf[g][kt], acc[1][g], 0, 0, 0);
            }
        }

        // ---- epilogue: activations + combine; fp32 h -> LDS out tile ----
        const bool lastChunk = ((m0 & 2047) == 2016);
        const int  b = m0 >> 11;
        const float K1 = 1.44269504f, K2 = 2.88539008f;
        #pragma unroll
        for (int mt = 0; mt < 2; ++mt) {
            #pragma unroll
            for (int reg = 0; reg < 4; ++reg) {
                float ai = clamp30(acc[mt][0][reg] + sv[0]);
                float af = clamp30(acc[mt][1][reg] + sv[1]);
                float ao = clamp30(acc[mt][2][reg] + sv[2]);
                float ag = clamp30(acc[mt][3][reg] + sv[3]);
                float ti = __builtin_amdgcn_exp2f(-K1 * ai);
                float tf = __builtin_amdgcn_exp2f(-K1 * af);
                float to = __builtin_amdgcn_exp2f(-K1 * ao);
                float tg = __builtin_amdgcn_exp2f(-K2 * ag);
                float fg = __builtin_amdgcn_rcpf(1.f + tf);                       // sigmoid(af)
                float ig = (1.f - tg) * __builtin_amdgcn_rcpf((1.f + ti) * (1.f + tg)); // sig(ai)*tanh(ag)
                float cv = clamp30(fg * c0v + ig);
                float tc = __builtin_amdgcn_exp2f(-K2 * cv);
                float hv = (1.f - tc) * __builtin_amdgcn_rcpf((1.f + to) * (1.f + tc)); // sig(ao)*tanh(cv)
                const int r = mt * 16 + hi * 4 + reg;
                *(float*)(lds + OB + r * LSTRO + col * 4) = hv;
                if (lastChunk && mt == 1 && reg == 3 && hi == 3)   // row t=2047
                    clast[b * 128 + col] = cv;
            }
        }

        // stage next chunk into other buffer (convert + LDS write)
        if (it + 1 < ITERS) {
            char* An = lds + ((it & 1) ? AB0 : AB1);
            #pragma unroll
            for (int j = 0; j < 2; ++j) {
                const int f = j * 512 + tid;
                uint2v p;
                p.x = packbf2(pf[j].x, pf[j].y);
                p.y = packbf2(pf[j].z, pf[j].w);
                *(uint2v*)(An + (f >> 5) * LSTR + (f & 31) * 8) = p;
            }
        }
        __syncthreads();

        // ---- store: fp32 rows of hidden_seq (T,B,1,H); 512B contiguous per row ----
        #pragma unroll
        for (int j = 0; j < 2; ++j) {
            const int f = j * 512 + tid;        // float4 index in 32x128 tile
            const int r = f >> 5;
            const int c = f & 31;
            float4 vv = *(const float4*)(lds + OB + r * LSTRO + c * 16);
            const int m = m0 + r;
            const int t = m & 2047;
            *(float4*)(hseq + (t * 256 + b) * 128 + c * 4) = vv;
            if (t == 2047)
                *(float4*)(hlast + b * 128 + c * 4) = vv;
        }
        __syncthreads();

        m0 += GRID * CHUNK;
    }
}

extern "C" void kernel_launch(void* const* d_in, const int* in_sizes, int n_in,
                              void* d_out, int out_size, void* d_ws, size_t ws_size,
                              hipStream_t stream) {
    (void)in_sizes; (void)n_in; (void)out_size; (void)d_ws; (void)ws_size;
    const float* x  = (const float*)d_in[0];
    const float* h0 = (const float*)d_in[1];
    const float* c0 = (const float*)d_in[2];
    // setup_inputs order: 3..6 = i (w_ii,w_hi,b_ii,b_hi), 7..10 = f, 11..14 = o, 15..18 = g
    lstm_main<<<dim3(GRID), dim3(THREADS), 0, stream>>>(
        x, h0, c0,
        (const float*)d_in[3],  (const float*)d_in[4],
        (const float*)d_in[5],  (const float*)d_in[6],
        (const float*)d_in[7],  (const float*)d_in[8],
        (const float*)d_in[9],  (const float*)d_in[10],
        (const float*)d_in[11], (const float*)d_in[12],
        (const float*)d_in[13], (const float*)d_in[14],
        (const float*)d_in[15], (const float*)d_in[16],
        (const float*)d_in[17], (const float*)d_in[18],
        (float*)d_out);
}